// Round 5
// baseline (896.535 us; speedup 1.0000x reference)
//
#include <hip/hip_runtime.h>
#include <cstdint>

typedef _Float16 f16_t;
typedef __attribute__((ext_vector_type(8))) _Float16 f16x8;
typedef __attribute__((ext_vector_type(4))) _Float16 f16x4;
typedef __attribute__((ext_vector_type(4))) float f32x4;

#define HP      160      // padded H (150 -> 160): h/c row stride, U K-dim
#define NCOL    640      // 160 j x 4 gates (P is [v][j][g] interleaved)
#define KXP     320      // padded X_SIZE (300 -> 320)
#define NNODES  524287
#define LEAF_S  262143
#define NVOCAB  50000
#define AST     168      // A_sh stride (f16): 16B-aligned, conflict-light
#define BST     36       // B_sh stride (f16): b64 ops, 16 distinct banks
#define CST     162      // C_sh stride (f16): conflict-free scalar access

__device__ __forceinline__ float frcp(float x) { return __builtin_amdgcn_rcpf(x); }
__device__ __forceinline__ float sigf(float x) { return frcp(1.0f + __expf(-x)); }
__device__ __forceinline__ float tanhf_(float x) {
  return 1.0f - 2.0f * frcp(1.0f + __expf(2.0f * x));
}
__device__ __forceinline__ f16x8 zero8() {
  f16x8 z;
#pragma unroll
  for (int i = 0; i < 8; ++i) z[i] = (_Float16)0.0f;
  return z;
}
__device__ __forceinline__ f32x4 zero4() {
  f32x4 z;
#pragma unroll
  for (int i = 0; i < 4; ++i) z[i] = 0.0f;
  return z;
}

// Stage 128 U-columns x 32 k into B_sh (stride 36, two b64 writes).
__device__ __forceinline__ void stage_B(const f16_t* __restrict__ UreT, f16_t* B_sh,
                                        int tid, int j0, int kk) {
#pragma unroll
  for (int i = 0; i < 2; ++i) {
    int ch = tid + 256 * i;
    int cidx = ch >> 2, kc = (ch & 3) * 8;
    int g = cidx >> 5, jj = cidx & 31;
    int col = g * HP + j0 + jj;
    f16x8 v = *(const f16x8*)&UreT[col * HP + kk + kc];
    f16x4 lo = {v[0], v[1], v[2], v[3]};
    f16x4 hi = {v[4], v[5], v[6], v[7]};
    *(f16x4*)&B_sh[cidx * BST + kc] = lo;
    *(f16x4*)&B_sh[cidx * BST + kc + 4] = hi;
  }
}
__device__ __forceinline__ f16x8 read_B(const f16_t* B_sh, int tile16, int q) {
  f16x4 lo = *(const f16x4*)&B_sh[tile16 * BST + q * 8];
  f16x4 hi = *(const f16x4*)&B_sh[tile16 * BST + q * 8 + 4];
  f16x8 v = {lo[0], lo[1], lo[2], lo[3], hi[0], hi[1], hi[2], hi[3]};
  return v;
}

// WreT[colIdx][k], colIdx = j*4+g (interleaved, matches P);
// UreT[col][k], col = g*160+j (g-major, matches B staging); bre interleaved.
__global__ void prep_params(const float* __restrict__ W_iou, const float* __restrict__ U_iou,
                            const float* __restrict__ b_iou, const float* __restrict__ W_f,
                            const float* __restrict__ U_f, const float* __restrict__ b_f,
                            f16_t* __restrict__ WreT, f16_t* __restrict__ UreT,
                            float* __restrict__ bre) {
  int idx = blockIdx.x * 256 + threadIdx.x;
  if (idx < NCOL * KXP) {
    int col = idx / KXP, k = idx % KXP;
    int j = col >> 2, g = col & 3;
    float v = 0.0f;
    if (k < 300 && j < 150) v = (g < 3) ? W_iou[k * 450 + g * 150 + j] : W_f[k * 150 + j];
    WreT[idx] = (f16_t)v;
  } else if (idx < NCOL * KXP + NCOL * HP) {
    int i2 = idx - NCOL * KXP;
    int col = i2 / HP, k = i2 % HP;
    int g = col / 160, j = col % 160;
    float v = 0.0f;
    if (k < 150 && j < 150) v = (g < 3) ? U_iou[k * 450 + g * 150 + j] : U_f[k * 150 + j];
    UreT[i2] = (f16_t)v;
  } else if (idx < NCOL * KXP + NCOL * HP + NCOL) {
    int col = idx - (NCOL * KXP + NCOL * HP);
    int j = col >> 2, g = col & 3;
    bre[col] = (j < 150) ? ((g < 3) ? b_iou[g * 150 + j] : b_f[j]) : 0.0f;
  }
}

// P[v][j][g] = emb @ W + b, fp16, 50000 x 640 (interleaved cols).
__global__ __launch_bounds__(256) void gemm_p(const float* __restrict__ emb,
                                              const f16_t* __restrict__ WreT,
                                              const float* __restrict__ bre,
                                              f16_t* __restrict__ P) {
  __shared__ __align__(16) f16_t A_sh[64 * 328];
  __shared__ __align__(16) f16_t B_sh[128 * 40];
  const int tid = threadIdx.x;
  const int wid = tid >> 6, lane = tid & 63, l15 = lane & 15, q = lane >> 4;
  const int row0 = blockIdx.x * 64;

#pragma unroll
  for (int i = 0; i < 10; ++i) {
    int ch = tid + 256 * i;
    int r = ch / 40, kc = (ch % 40) * 8;
    int grow = row0 + r;
    f16x8 hv;
    if (grow < NVOCAB && kc + 8 <= 300) {
      float4 a = *(const float4*)&emb[grow * 300 + kc];
      float4 b = *(const float4*)&emb[grow * 300 + kc + 4];
      hv[0] = (_Float16)a.x; hv[1] = (_Float16)a.y; hv[2] = (_Float16)a.z; hv[3] = (_Float16)a.w;
      hv[4] = (_Float16)b.x; hv[5] = (_Float16)b.y; hv[6] = (_Float16)b.z; hv[7] = (_Float16)b.w;
    } else {
#pragma unroll
      for (int e = 0; e < 8; ++e) {
        int k = kc + e;
        float v = (grow < NVOCAB && k < 300) ? emb[grow * 300 + k] : 0.0f;
        hv[e] = (_Float16)v;
      }
    }
    *(f16x8*)&A_sh[r * 328 + kc] = hv;
  }
  __syncthreads();

  for (int bn = 0; bn < 5; ++bn) {
    const int col0 = bn * 128;
    f32x4 acc[8];
#pragma unroll
    for (int t = 0; t < 8; ++t) acc[t] = zero4();
    for (int kk = 0; kk < KXP; kk += 32) {
#pragma unroll
      for (int i = 0; i < 2; ++i) {
        int ch = tid + 256 * i;
        int cidx = ch >> 2, kc = (ch & 3) * 8;
        *(f16x8*)&B_sh[cidx * 40 + kc] =
            *(const f16x8*)&WreT[(col0 + cidx) * KXP + kk + kc];
      }
      __syncthreads();
      f16x8 af = *(const f16x8*)&A_sh[(16 * wid + l15) * 328 + kk + q * 8];
#pragma unroll
      for (int t = 0; t < 8; ++t) {
        f16x8 bfr = *(const f16x8*)&B_sh[(t * 16 + l15) * 40 + q * 8];
        acc[t] = __builtin_amdgcn_mfma_f32_16x16x32_f16(af, bfr, acc[t], 0, 0, 0);
      }
      __syncthreads();
    }
#pragma unroll
    for (int t = 0; t < 8; ++t) {
      int col = col0 + t * 16 + l15;
      float bias = bre[col];
#pragma unroll
      for (int r2 = 0; r2 < 4; ++r2) {
        int row = row0 + 16 * wid + q * 4 + r2;
        if (row < NVOCAB) P[(long)row * NCOL + col] = (f16_t)(acc[t][r2] + bias);
      }
    }
  }
}

// Vocab-space leaf h/c tables: Hleaf[v][j], Cleaf[v][j] (f16).
__global__ void leafhc_kernel(const f16_t* __restrict__ P, f16_t* __restrict__ Hleaf,
                              f16_t* __restrict__ Cleaf) {
  int idx = blockIdx.x * 256 + threadIdx.x;
  if (idx >= NVOCAB * 80) return;
  int v = idx / 80, t = idx % 80;
  f16x8 pk = *(const f16x8*)&P[(long)v * NCOL + t * 8];
#pragma unroll
  for (int e = 0; e < 2; ++e) {
    float iv = (float)pk[e * 4 + 0], ov = (float)pk[e * 4 + 1], uv = (float)pk[e * 4 + 2];
    float cl = sigf(iv) * tanhf_(uv);
    float hl = sigf(ov) * tanhf_(cl);
    Hleaf[(long)v * HP + t * 2 + e] = (f16_t)hl;   // pads (t>=75) exactly 0
    Cleaf[(long)v * HP + t * 2 + e] = (f16_t)cl;
  }
}

// Fused levels 17+16: 64 leaf children -> 32 L17 parents -> 16 L16 nodes.
// Consumer projections: leaves from A_sh, L17 parents from A2_sh.
__global__ __launch_bounds__(256, 3) void fused17_kernel(
    const int* __restrict__ x_id, const f16_t* __restrict__ P,
    const f16_t* __restrict__ UreT, const f16_t* __restrict__ Hleaf,
    const f16_t* __restrict__ Cleaf, f16_t* __restrict__ Hout,
    f16_t* __restrict__ Cout, const float* __restrict__ W_out,
    const float* __restrict__ b_out, float* __restrict__ out) {
  __shared__ __align__(16) f16_t A_sh[64 * AST];
  __shared__ __align__(16) f16_t A2_sh[32 * AST];
  __shared__ __align__(16) f16_t B_sh[128 * BST];
  __shared__ f16_t C_sh[32 * CST];
  __shared__ __align__(16) f16_t Wo16[160 * 8];
  const int tid = threadIdx.x;
  const int wid = tid >> 6, lane = tid & 63, l15 = lane & 15, q = lane >> 4;
  const int p0 = blockIdx.x * 32;
  const int s1 = (1 << 17) - 1;
  const long childbase = (long)LEAF_S + 2 * p0;

  for (int idx = tid; idx < 1280; idx += 256) {
    int j = idx >> 3, m = idx & 7;
    Wo16[idx] = (j < 150 && m < 5) ? (f16_t)W_out[j * 5 + m] : (f16_t)0.0f;
  }

  // stage A: 64 leaf h rows gathered from Hleaf
#pragma unroll
  for (int i = 0; i < 5; ++i) {
    int ch = tid + 256 * i;
    int r = ch / 20, kc = (ch % 20) * 8;
    int xv = x_id[childbase + r];
    *(f16x8*)&A_sh[r * AST + kc] = *(const f16x8*)&Hleaf[(long)xv * HP + kc];
  }
  __syncthreads();

  // consumer projection: 64 leaves from A_sh
  {
    const int row = 16 * wid + l15;
    const int jb = q * 40;
    float o[5] = {0, 0, 0, 0, 0};
#pragma unroll
    for (int jc = 0; jc < 5; ++jc) {
      f16x8 hv8 = *(const f16x8*)&A_sh[row * AST + jb + jc * 8];
#pragma unroll
      for (int e = 0; e < 8; ++e) {
        float hv = (float)hv8[e];
        f16x8 w8 = *(const f16x8*)&Wo16[(jb + jc * 8 + e) * 8];
#pragma unroll
        for (int m = 0; m < 5; ++m) o[m] += hv * (float)w8[m];
      }
    }
#pragma unroll
    for (int m = 0; m < 5; ++m) {
      float v = o[m];
      v += __shfl_xor(v, 16);
      v += __shfl_xor(v, 32);
      o[m] = v;
    }
    if (q == 0) {
      long base = (childbase + row) * 5;
#pragma unroll
      for (int m = 0; m < 5; ++m) out[base + m] = o[m] + b_out[m];
    }
  }

  // pass 1: L17, 32 parents
  int xvp[2], xvl[2], xvr[2];
#pragma unroll
  for (int rr = 0; rr < 2; ++rr) {
    int pl = 8 * wid + 2 * q + rr;
    long pn = (long)s1 + p0 + pl;
    xvp[rr] = x_id[pn];
    xvl[rr] = x_id[childbase + 2 * pl];
    xvr[rr] = x_id[childbase + 2 * pl + 1];
  }

  for (int jt = 0; jt < 5; ++jt) {
    const int j0 = jt * 32;
    f32x4 acc[4][2];
#pragma unroll
    for (int g = 0; g < 4; ++g)
#pragma unroll
      for (int jh = 0; jh < 2; ++jh) acc[g][jh] = zero4();

    for (int kk = 0; kk < HP; kk += 32) {
      stage_B(UreT, B_sh, tid, j0, kk);
      __syncthreads();
      f16x8 af = *(const f16x8*)&A_sh[(16 * wid + l15) * AST + kk + q * 8];
#pragma unroll
      for (int g = 0; g < 4; ++g)
#pragma unroll
        for (int jh = 0; jh < 2; ++jh) {
          f16x8 bfr = read_B(B_sh, g * 32 + jh * 16 + l15, q);
          acc[g][jh] = __builtin_amdgcn_mfma_f32_16x16x32_f16(af, bfr, acc[g][jh], 0, 0, 0);
        }
      __syncthreads();
    }

#pragma unroll
    for (int rr = 0; rr < 2; ++rr) {
      const int r = rr * 2;
      const int pl = 8 * wid + 2 * q + rr;
      const f16_t* Prp = P + (long)xvp[rr] * NCOL;
      const f16_t* Prl = Cleaf + (long)xvl[rr] * HP;
      const f16_t* Prr_ = Cleaf + (long)xvr[rr] * HP;
#pragma unroll
      for (int jh = 0; jh < 2; ++jh) {
        const int j = j0 + jh * 16 + l15;
        f16x4 pp = *(const f16x4*)&Prp[j * 4];
        float ipre = (float)pp[0] + acc[0][jh][r] + acc[0][jh][r + 1];
        float opre = (float)pp[1] + acc[1][jh][r] + acc[1][jh][r + 1];
        float upre = (float)pp[2] + acc[2][jh][r] + acc[2][jh][r + 1];
        float pf   = (float)pp[3];
        float fl = sigf(pf + acc[3][jh][r]);
        float fr = sigf(pf + acc[3][jh][r + 1]);
        float clv = (float)Prl[j];
        float crv = (float)Prr_[j];
        float cn = sigf(ipre) * tanhf_(upre) + fl * clv + fr * crv;
        float hn = sigf(opre) * tanhf_(cn);
        A2_sh[pl * AST + j] = (f16_t)hn;
        C_sh[pl * CST + j] = (f16_t)cn;
      }
    }
  }
  __syncthreads();   // A2/C complete

  // consumer projection: 32 L17 parents from A2_sh
  if (wid < 2) {
    const int row = 16 * wid + l15;
    const int jb = q * 40;
    float o[5] = {0, 0, 0, 0, 0};
#pragma unroll
    for (int jc = 0; jc < 5; ++jc) {
      f16x8 hv8 = *(const f16x8*)&A2_sh[row * AST + jb + jc * 8];
#pragma unroll
      for (int e = 0; e < 8; ++e) {
        float hv = (float)hv8[e];
        f16x8 w8 = *(const f16x8*)&Wo16[(jb + jc * 8 + e) * 8];
#pragma unroll
        for (int m = 0; m < 5; ++m) o[m] += hv * (float)w8[m];
      }
    }
#pragma unroll
    for (int m = 0; m < 5; ++m) {
      float v = o[m];
      v += __shfl_xor(v, 16);
      v += __shfl_xor(v, 32);
      o[m] = v;
    }
    if (q == 0) {
      long base = ((long)s1 + p0 + row) * 5;
#pragma unroll
      for (int m = 0; m < 5; ++m) out[base + m] = o[m] + b_out[m];
    }
  }

  // pass 2: L16, 16 nodes (waves 0,1 compute; all stage B)
  const int s2 = (s1 - 1) >> 1;
  const int p02 = p0 >> 1;
  const bool act2 = (wid < 2);
  int xvp2[2];
#pragma unroll
  for (int rr = 0; rr < 2; ++rr) {
    int pl = 8 * wid + 2 * q + rr;
    long pn = (long)s2 + p02 + (act2 ? pl : 0);
    xvp2[rr] = x_id[pn];
  }

  for (int jt = 0; jt < 5; ++jt) {
    const int j0 = jt * 32;
    f32x4 acc[4][2];
#pragma unroll
    for (int g = 0; g < 4; ++g)
#pragma unroll
      for (int jh = 0; jh < 2; ++jh) acc[g][jh] = zero4();

    for (int kk = 0; kk < HP; kk += 32) {
      stage_B(UreT, B_sh, tid, j0, kk);
      __syncthreads();
      if (act2) {
        f16x8 af = *(const f16x8*)&A2_sh[(16 * wid + l15) * AST + kk + q * 8];
#pragma unroll
        for (int g = 0; g < 4; ++g)
#pragma unroll
          for (int jh = 0; jh < 2; ++jh) {
            f16x8 bfr = read_B(B_sh, g * 32 + jh * 16 + l15, q);
            acc[g][jh] = __builtin_amdgcn_mfma_f32_16x16x32_f16(af, bfr, acc[g][jh], 0, 0, 0);
          }
      }
      __syncthreads();
    }

    if (act2) {
#pragma unroll
      for (int rr = 0; rr < 2; ++rr) {
        const int r = rr * 2;
        const int lr0 = 16 * wid + q * 4 + r;   // 0..31
        const int pl = lr0 >> 1;                // 0..15
        const f16_t* Prp = P + (long)xvp2[rr] * NCOL;
#pragma unroll
        for (int jh = 0; jh < 2; ++jh) {
          const int j = j0 + jh * 16 + l15;
          f16x4 pp = *(const f16x4*)&Prp[j * 4];
          float ipre = (float)pp[0] + acc[0][jh][r] + acc[0][jh][r + 1];
          float opre = (float)pp[1] + acc[1][jh][r] + acc[1][jh][r + 1];
          float upre = (float)pp[2] + acc[2][jh][r] + acc[2][jh][r + 1];
          float pf   = (float)pp[3];
          float fl = sigf(pf + acc[3][jh][r]);
          float fr = sigf(pf + acc[3][jh][r + 1]);
          float clv = (float)C_sh[lr0 * CST + j];
          float crv = (float)C_sh[(lr0 + 1) * CST + j];
          float cn = sigf(ipre) * tanhf_(upre) + fl * clv + fr * crv;
          float hn = sigf(opre) * tanhf_(cn);
          Hout[(long)(p02 + pl) * HP + j] = (f16_t)hn;
          Cout[(long)(p02 + pl) * HP + j] = (f16_t)cn;
        }
      }
    }
  }
}

// Simple single level: 32 parents/block (M multiple of 32, M>=64).
// Consumer projection of the 64 staged children.
__global__ __launch_bounds__(256, 4) void level_k(
    const int* __restrict__ x_id, const f16_t* __restrict__ P,
    const f16_t* __restrict__ UreT, const f16_t* __restrict__ Hc,
    const f16_t* __restrict__ Cc, f16_t* __restrict__ Hp,
    f16_t* __restrict__ Cp, const float* __restrict__ W_out,
    const float* __restrict__ b_out, float* __restrict__ out, int s, int M) {
  __shared__ __align__(16) f16_t A_sh[64 * AST];
  __shared__ __align__(16) f16_t B_sh[128 * BST];
  __shared__ __align__(16) float Wo[160 * 8];
  const int tid = threadIdx.x;
  const int wid = tid >> 6, lane = tid & 63, l15 = lane & 15, q = lane >> 4;
  const int p0 = blockIdx.x * 32;
  const long childbase = 2L * s + 1 + 2 * p0;   // abs node id of first child

  for (int idx = tid; idx < 1280; idx += 256) {
    int j = idx >> 3, m = idx & 7;
    Wo[idx] = (j < 150 && m < 5) ? W_out[j * 5 + m] : 0.0f;
  }

#pragma unroll
  for (int i = 0; i < 5; ++i) {
    int ch = tid + 256 * i;
    int r = ch / 20, kc = (ch % 20) * 8;
    *(f16x8*)&A_sh[r * AST + kc] = *(const f16x8*)&Hc[(long)(2 * p0 + r) * HP + kc];
  }
  __syncthreads();

  // consumer projection: the 64 staged children (level s's child level)
  {
    const int row = 16 * wid + l15;
    const int jb = q * 40;
    float o[5] = {0, 0, 0, 0, 0};
#pragma unroll
    for (int jc = 0; jc < 5; ++jc) {
      f16x8 hv8 = *(const f16x8*)&A_sh[row * AST + jb + jc * 8];
#pragma unroll
      for (int e = 0; e < 8; ++e) {
        float hv = (float)hv8[e];
        int j = jb + jc * 8 + e;
        float4 w4 = *(const float4*)&Wo[j * 8];
        float w5 = Wo[j * 8 + 4];
        o[0] += hv * w4.x; o[1] += hv * w4.y; o[2] += hv * w4.z;
        o[3] += hv * w4.w; o[4] += hv * w5;
      }
    }
#pragma unroll
    for (int m = 0; m < 5; ++m) {
      float v = o[m];
      v += __shfl_xor(v, 16);
      v += __shfl_xor(v, 32);
      o[m] = v;
    }
    if (q == 0) {
      long base = (childbase + row) * 5;
#pragma unroll
      for (int m = 0; m < 5; ++m) out[base + m] = o[m] + b_out[m];
    }
  }

  int xvp[2];
#pragma unroll
  for (int rr = 0; rr < 2; ++rr) {
    int pl = 8 * wid + 2 * q + rr;
    xvp[rr] = x_id[(long)s + p0 + pl];
  }

  for (int jt = 0; jt < 5; ++jt) {
    const int j0 = jt * 32;
    f32x4 acc[4][2];
#pragma unroll
    for (int g = 0; g < 4; ++g)
#pragma unroll
      for (int jh = 0; jh < 2; ++jh) acc[g][jh] = zero4();

    for (int kk = 0; kk < HP; kk += 32) {
      stage_B(UreT, B_sh, tid, j0, kk);
      __syncthreads();
      f16x8 af = *(const f16x8*)&A_sh[(16 * wid + l15) * AST + kk + q * 8];
#pragma unroll
      for (int g = 0; g < 4; ++g)
#pragma unroll
        for (int jh = 0; jh < 2; ++jh) {
          f16x8 bfr = read_B(B_sh, g * 32 + jh * 16 + l15, q);
          acc[g][jh] = __builtin_amdgcn_mfma_f32_16x16x32_f16(af, bfr, acc[g][jh], 0, 0, 0);
        }
      __syncthreads();
    }

#pragma unroll
    for (int rr = 0; rr < 2; ++rr) {
      const int r = rr * 2;
      const int lr0 = 16 * wid + q * 4 + r;
      const int pl = lr0 >> 1;
      const f16_t* Prp = P + (long)xvp[rr] * NCOL;
#pragma unroll
      for (int jh = 0; jh < 2; ++jh) {
        const int j = j0 + jh * 16 + l15;
        f16x4 pp = *(const f16x4*)&Prp[j * 4];
        float ipre = (float)pp[0] + acc[0][jh][r] + acc[0][jh][r + 1];
        float opre = (float)pp[1] + acc[1][jh][r] + acc[1][jh][r + 1];
        float upre = (float)pp[2] + acc[2][jh][r] + acc[2][jh][r + 1];
        float pf   = (float)pp[3];
        float fl = sigf(pf + acc[3][jh][r]);
        float fr = sigf(pf + acc[3][jh][r + 1]);
        float clv = (float)Cc[(long)(2 * p0 + lr0) * HP + j];
        float crv = (float)Cc[(long)(2 * p0 + lr0 + 1) * HP + j];
        float cn = sigf(ipre) * tanhf_(upre) + fl * clv + fr * crv;
        float hn = sigf(opre) * tanhf_(cn);
        Hp[(long)(p0 + pl) * HP + j] = (f16_t)hn;
        Cp[(long)(p0 + pl) * HP + j] = (f16_t)cn;
      }
    }
  }
}

// Levels 5..0 in one block + root projection. Level L reads (L odd ? X : Y),
// writes (L even ? X : Y).
__global__ __launch_bounds__(256, 4) void tail_kernel(
    const int* __restrict__ x_id, const f16_t* __restrict__ P,
    const f16_t* __restrict__ UreT, f16_t* __restrict__ HX, f16_t* __restrict__ HY,
    f16_t* __restrict__ CX, f16_t* __restrict__ CY, const float* __restrict__ W_out,
    const float* __restrict__ b_out, float* __restrict__ out) {
  __shared__ __align__(16) f16_t A_sh[64 * AST];
  __shared__ __align__(16) f16_t B_sh[128 * BST];
  __shared__ __align__(16) float Wo[160 * 8];
  const int tid = threadIdx.x;
  const int wid = tid >> 6, lane = tid & 63, l15 = lane & 15, q = lane >> 4;

  for (int idx = tid; idx < 1280; idx += 256) {
    int j = idx >> 3, m = idx & 7;
    Wo[idx] = (j < 150 && m < 5) ? W_out[j * 5 + m] : 0.0f;
  }

  for (int lvl = 5; lvl >= 0; --lvl) {
    const int s = (1 << lvl) - 1, M = 1 << lvl;
    const f16_t* hc = (lvl & 1) ? HX : HY;
    const f16_t* cc = (lvl & 1) ? CX : CY;
    f16_t* hp = (lvl & 1) ? HY : HX;
    f16_t* cp = (lvl & 1) ? CY : CX;
    int rowsValid = 2 * M;
    if (rowsValid > 64) rowsValid = 64;

    __syncthreads();
#pragma unroll
    for (int i = 0; i < 5; ++i) {
      int ch = tid + 256 * i;
      int r = ch / 20, kc = (ch % 20) * 8;
      f16x8 v = (r < rowsValid) ? *(const f16x8*)&hc[(long)r * HP + kc] : zero8();
      *(f16x8*)&A_sh[r * AST + kc] = v;
    }
    __syncthreads();

    // projection of children (level lvl+1): nodes (2s+1)+row
    {
      const int row = 16 * wid + l15;
      if (row < rowsValid) {
        const int jb = q * 40;
        float o[5] = {0, 0, 0, 0, 0};
#pragma unroll
        for (int jc = 0; jc < 5; ++jc) {
          f16x8 hv8 = *(const f16x8*)&A_sh[row * AST + jb + jc * 8];
#pragma unroll
          for (int e = 0; e < 8; ++e) {
            float hv = (float)hv8[e];
            int j = jb + jc * 8 + e;
            float4 w4 = *(const float4*)&Wo[j * 8];
            float w5 = Wo[j * 8 + 4];
            o[0] += hv * w4.x; o[1] += hv * w4.y; o[2] += hv * w4.z;
            o[3] += hv * w4.w; o[4] += hv * w5;
          }
        }
#pragma unroll
        for (int m = 0; m < 5; ++m) {
          float v = o[m];
          v += __shfl_xor(v, 16);
          v += __shfl_xor(v, 32);
          o[m] = v;
        }
        if (q == 0) {
          long base = (long)(2 * s + 1 + row) * 5;
#pragma unroll
          for (int m = 0; m < 5; ++m) out[base + m] = o[m] + b_out[m];
        }
      }
    }

    int xvp[2]; bool valid[2];
#pragma unroll
    for (int rr = 0; rr < 2; ++rr) {
      int pl = 8 * wid + 2 * q + rr;
      valid[rr] = pl < M;
      xvp[rr] = x_id[(long)s + (valid[rr] ? pl : 0)];
    }

    for (int jt = 0; jt < 5; ++jt) {
      const int j0 = jt * 32;
      f32x4 acc[4][2];
#pragma unroll
      for (int g = 0; g < 4; ++g)
#pragma unroll
        for (int jh = 0; jh < 2; ++jh) acc[g][jh] = zero4();

      for (int kk = 0; kk < HP; kk += 32) {
        stage_B(UreT, B_sh, tid, j0, kk);
        __syncthreads();
        f16x8 af = *(const f16x8*)&A_sh[(16 * wid + l15) * AST + kk + q * 8];
#pragma unroll
        for (int g = 0; g < 4; ++g)
#pragma unroll
          for (int jh = 0; jh < 2; ++jh) {
            f16x8 bfr = read_B(B_sh, g * 32 + jh * 16 + l15, q);
            acc[g][jh] = __builtin_amdgcn_mfma_f32_16x16x32_f16(af, bfr, acc[g][jh], 0, 0, 0);
          }
        __syncthreads();
      }

#pragma unroll
      for (int rr = 0; rr < 2; ++rr) {
        const int r = rr * 2;
        const int lr0 = 16 * wid + q * 4 + r;
        const int pl = lr0 >> 1;
        const f16_t* Prp = P + (long)xvp[rr] * NCOL;
#pragma unroll
        for (int jh = 0; jh < 2; ++jh) {
          const int j = j0 + jh * 16 + l15;
          f16x4 pp = *(const f16x4*)&Prp[j * 4];
          float ipre = (float)pp[0] + acc[0][jh][r] + acc[0][jh][r + 1];
          float opre = (float)pp[1] + acc[1][jh][r] + acc[1][jh][r + 1];
          float upre = (float)pp[2] + acc[2][jh][r] + acc[2][jh][r + 1];
          float pf   = (float)pp[3];
          float fl = sigf(pf + acc[3][jh][r]);
          float fr = sigf(pf + acc[3][jh][r + 1]);
          float clv = valid[rr] ? (float)cc[(long)lr0 * HP + j] : 0.0f;
          float crv = valid[rr] ? (float)cc[(long)(lr0 + 1) * HP + j] : 0.0f;
          float cn = sigf(ipre) * tanhf_(upre) + fl * clv + fr * crv;
          float hn = sigf(opre) * tanhf_(cn);
          if (valid[rr]) {
            hp[(long)pl * HP + j] = (f16_t)hn;
            cp[(long)pl * HP + j] = (f16_t)cn;
          }
        }
      }
    }
    __threadfence();
  }

  __threadfence();
  __syncthreads();
  // root (node 0): h in HX row 0
  if (tid < 64) {
    float o[5] = {0, 0, 0, 0, 0};
    for (int j = tid; j < 150; j += 64) {
      float hv = (float)HX[j];
      float4 w4 = *(const float4*)&Wo[j * 8];
      float w5 = Wo[j * 8 + 4];
      o[0] += hv * w4.x; o[1] += hv * w4.y; o[2] += hv * w4.z;
      o[3] += hv * w4.w; o[4] += hv * w5;
    }
#pragma unroll
    for (int m = 0; m < 5; ++m) {
      float v = o[m];
      v += __shfl_xor(v, 1);
      v += __shfl_xor(v, 2);
      v += __shfl_xor(v, 4);
      v += __shfl_xor(v, 8);
      v += __shfl_xor(v, 16);
      v += __shfl_xor(v, 32);
      o[m] = v;
    }
    if (tid == 0) {
#pragma unroll
      for (int m = 0; m < 5; ++m) out[m] = o[m] + b_out[m];
    }
  }
}

extern "C" void kernel_launch(void* const* d_in, const int* in_sizes, int n_in,
                              void* d_out, int out_size, void* d_ws, size_t ws_size,
                              hipStream_t stream) {
  const int* x_id   = (const int*)d_in[0];
  const float* emb  = (const float*)d_in[1];
  const float* W_iou = (const float*)d_in[2];
  const float* U_iou = (const float*)d_in[3];
  const float* b_iou = (const float*)d_in[4];
  const float* W_f   = (const float*)d_in[5];
  const float* U_f   = (const float*)d_in[6];
  const float* b_f   = (const float*)d_in[7];
  const float* W_out = (const float*)d_in[8];
  const float* b_out = (const float*)d_in[9];
  float* out = (float*)d_out;
  char* ws = (char*)d_ws;

  // workspace carve (bytes): total 180,503,040
  f16_t* WreT  = (f16_t*)(ws + 0);              // 409,600
  f16_t* UreT  = (f16_t*)(ws + 409600);         // 204,800
  float* bre   = (float*)(ws + 614400);         // 2,560
  f16_t* P     = (f16_t*)(ws + 616960);         // 64,000,000
  f16_t* Hleaf = (f16_t*)(ws + 64616960);       // 16,000,000
  f16_t* Cleaf = (f16_t*)(ws + 80616960);       // 16,000,000
  f16_t* HX    = (f16_t*)(ws + 96616960);       // 20,971,520 (65536 rows)
  f16_t* HY    = (f16_t*)(ws + 117588480);      // 20,971,520
  f16_t* CX    = (f16_t*)(ws + 138560000);      // 20,971,520
  f16_t* CY    = (f16_t*)(ws + 159531520);      // 20,971,520

  prep_params<<<1203, 256, 0, stream>>>(W_iou, U_iou, b_iou, W_f, U_f, b_f, WreT, UreT, bre);
  gemm_p<<<782, 256, 0, stream>>>(emb, WreT, bre, P);
  leafhc_kernel<<<15625, 256, 0, stream>>>(P, Hleaf, Cleaf);

  // levels 17+16 -> HX/CX (L16 even -> X)
  fused17_kernel<<<4096, 256, 0, stream>>>(x_id, P, UreT, Hleaf, Cleaf, HX, CX,
                                           W_out, b_out, out);

  // levels 15..6: level L reads (L odd ? X : Y), writes (L even ? X : Y)
  for (int L = 15; L >= 6; --L) {
    int s = (1 << L) - 1, M = 1 << L;
    const f16_t* hc = (L & 1) ? HX : HY;
    const f16_t* cc = (L & 1) ? CX : CY;
    f16_t* hp = (L & 1) ? HY : HX;
    f16_t* cp = (L & 1) ? CY : CX;
    level_k<<<M / 32, 256, 0, stream>>>(x_id, P, UreT, hc, cc, hp, cp,
                                        W_out, b_out, out, s, M);
  }

  tail_kernel<<<1, 256, 0, stream>>>(x_id, P, UreT, HX, HY, CX, CY, W_out, b_out, out);

  (void)in_sizes; (void)n_in; (void)out_size; (void)ws_size;
}

// Round 6
// 885.075 us; speedup vs baseline: 1.0129x; 1.0129x over previous
//
#include <hip/hip_runtime.h>
#include <cstdint>

typedef _Float16 f16_t;
typedef __attribute__((ext_vector_type(8))) _Float16 f16x8;
typedef __attribute__((ext_vector_type(4))) _Float16 f16x4;
typedef __attribute__((ext_vector_type(4))) float f32x4;

#define HP      160      // padded H (150 -> 160): h/c row stride, U K-dim
#define NCOL    640      // 160 j x 4 gates (P is [v][j][g] interleaved)
#define KXP     320      // padded X_SIZE (300 -> 320)
#define LEAF_S  262143
#define NVOCAB  50000
#define AST     168      // A2_sh stride (f16)
#define BST     36       // B_sh stride (f16)
#define CST     162      // C_sh stride (f16)

__device__ __forceinline__ float frcp(float x) { return __builtin_amdgcn_rcpf(x); }
__device__ __forceinline__ float sigf(float x) { return frcp(1.0f + __expf(-x)); }
__device__ __forceinline__ float tanhf_(float x) {
  return 1.0f - 2.0f * frcp(1.0f + __expf(2.0f * x));
}
__device__ __forceinline__ f16x8 zero8() {
  f16x8 z;
#pragma unroll
  for (int i = 0; i < 8; ++i) z[i] = (_Float16)0.0f;
  return z;
}
__device__ __forceinline__ f32x4 zero4() {
  f32x4 z;
#pragma unroll
  for (int i = 0; i < 4; ++i) z[i] = 0.0f;
  return z;
}

// Stage 128 U-columns x 32 k into B_sh (stride 36, two b64 writes).
__device__ __forceinline__ void stage_B(const f16_t* __restrict__ UreT, f16_t* B_sh,
                                        int tid, int j0, int kk) {
#pragma unroll
  for (int i = 0; i < 2; ++i) {
    int ch = tid + 256 * i;
    int cidx = ch >> 2, kc = (ch & 3) * 8;
    int g = cidx >> 5, jj = cidx & 31;
    int col = g * HP + j0 + jj;
    f16x8 v = *(const f16x8*)&UreT[col * HP + kk + kc];
    f16x4 lo = {v[0], v[1], v[2], v[3]};
    f16x4 hi = {v[4], v[5], v[6], v[7]};
    *(f16x4*)&B_sh[cidx * BST + kc] = lo;
    *(f16x4*)&B_sh[cidx * BST + kc + 4] = hi;
  }
}
__device__ __forceinline__ f16x8 read_B(const f16_t* B_sh, int tile16, int q) {
  f16x4 lo = *(const f16x4*)&B_sh[tile16 * BST + q * 8];
  f16x4 hi = *(const f16x4*)&B_sh[tile16 * BST + q * 8 + 4];
  f16x8 v = {lo[0], lo[1], lo[2], lo[3], hi[0], hi[1], hi[2], hi[3]};
  return v;
}

// WreT[colIdx][k], colIdx = j*4+g (interleaved, matches P);
// UreT[col][k], col = g*160+j (g-major); bre interleaved.
__global__ void prep_params(const float* __restrict__ W_iou, const float* __restrict__ U_iou,
                            const float* __restrict__ b_iou, const float* __restrict__ W_f,
                            const float* __restrict__ U_f, const float* __restrict__ b_f,
                            f16_t* __restrict__ WreT, f16_t* __restrict__ UreT,
                            float* __restrict__ bre) {
  int idx = blockIdx.x * 256 + threadIdx.x;
  if (idx < NCOL * KXP) {
    int col = idx / KXP, k = idx % KXP;
    int j = col >> 2, g = col & 3;
    float v = 0.0f;
    if (k < 300 && j < 150) v = (g < 3) ? W_iou[k * 450 + g * 150 + j] : W_f[k * 150 + j];
    WreT[idx] = (f16_t)v;
  } else if (idx < NCOL * KXP + NCOL * HP) {
    int i2 = idx - NCOL * KXP;
    int col = i2 / HP, k = i2 % HP;
    int g = col / 160, j = col % 160;
    float v = 0.0f;
    if (k < 150 && j < 150) v = (g < 3) ? U_iou[k * 450 + g * 150 + j] : U_f[k * 150 + j];
    UreT[i2] = (f16_t)v;
  } else if (idx < NCOL * KXP + NCOL * HP + NCOL) {
    int col = idx - (NCOL * KXP + NCOL * HP);
    int j = col >> 2, g = col & 3;
    bre[col] = (j < 150) ? ((g < 3) ? b_iou[g * 150 + j] : b_f[j]) : 0.0f;
  }
}

// P[v][j][g] = emb @ W + b, fp16, 50000 x 640 (interleaved cols).
__global__ __launch_bounds__(256) void gemm_p(const float* __restrict__ emb,
                                              const f16_t* __restrict__ WreT,
                                              const float* __restrict__ bre,
                                              f16_t* __restrict__ P) {
  __shared__ __align__(16) f16_t A_sh[64 * 328];
  __shared__ __align__(16) f16_t B_sh[128 * 40];
  const int tid = threadIdx.x;
  const int wid = tid >> 6, lane = tid & 63, l15 = lane & 15, q = lane >> 4;
  const int row0 = blockIdx.x * 64;

#pragma unroll
  for (int i = 0; i < 10; ++i) {
    int ch = tid + 256 * i;
    int r = ch / 40, kc = (ch % 40) * 8;
    int grow = row0 + r;
    f16x8 hv;
    if (grow < NVOCAB && kc + 8 <= 300) {
      float4 a = *(const float4*)&emb[grow * 300 + kc];
      float4 b = *(const float4*)&emb[grow * 300 + kc + 4];
      hv[0] = (_Float16)a.x; hv[1] = (_Float16)a.y; hv[2] = (_Float16)a.z; hv[3] = (_Float16)a.w;
      hv[4] = (_Float16)b.x; hv[5] = (_Float16)b.y; hv[6] = (_Float16)b.z; hv[7] = (_Float16)b.w;
    } else {
#pragma unroll
      for (int e = 0; e < 8; ++e) {
        int k = kc + e;
        float v = (grow < NVOCAB && k < 300) ? emb[grow * 300 + k] : 0.0f;
        hv[e] = (_Float16)v;
      }
    }
    *(f16x8*)&A_sh[r * 328 + kc] = hv;
  }
  __syncthreads();

  for (int bn = 0; bn < 5; ++bn) {
    const int col0 = bn * 128;
    f32x4 acc[8];
#pragma unroll
    for (int t = 0; t < 8; ++t) acc[t] = zero4();
    for (int kk = 0; kk < KXP; kk += 32) {
#pragma unroll
      for (int i = 0; i < 2; ++i) {
        int ch = tid + 256 * i;
        int cidx = ch >> 2, kc = (ch & 3) * 8;
        *(f16x8*)&B_sh[cidx * 40 + kc] =
            *(const f16x8*)&WreT[(col0 + cidx) * KXP + kk + kc];
      }
      __syncthreads();
      f16x8 af = *(const f16x8*)&A_sh[(16 * wid + l15) * 328 + kk + q * 8];
#pragma unroll
      for (int t = 0; t < 8; ++t) {
        f16x8 bfr = *(const f16x8*)&B_sh[(t * 16 + l15) * 40 + q * 8];
        acc[t] = __builtin_amdgcn_mfma_f32_16x16x32_f16(af, bfr, acc[t], 0, 0, 0);
      }
      __syncthreads();
    }
#pragma unroll
    for (int t = 0; t < 8; ++t) {
      int col = col0 + t * 16 + l15;
      float bias = bre[col];
#pragma unroll
      for (int r2 = 0; r2 < 4; ++r2) {
        int row = row0 + 16 * wid + q * 4 + r2;
        if (row < NVOCAB) P[(long)row * NCOL + col] = (f16_t)(acc[t][r2] + bias);
      }
    }
  }
}

// Vocab-space leaf h/c tables: Hleaf[v][j], Cleaf[v][j] (f16).
__global__ void leafhc_kernel(const f16_t* __restrict__ P, f16_t* __restrict__ Hleaf,
                              f16_t* __restrict__ Cleaf) {
  int idx = blockIdx.x * 256 + threadIdx.x;
  if (idx >= NVOCAB * 80) return;
  int v = idx / 80, t = idx % 80;
  f16x8 pk = *(const f16x8*)&P[(long)v * NCOL + t * 8];
#pragma unroll
  for (int e = 0; e < 2; ++e) {
    float iv = (float)pk[e * 4 + 0], ov = (float)pk[e * 4 + 1], uv = (float)pk[e * 4 + 2];
    float cl = sigf(iv) * tanhf_(uv);
    float hl = sigf(ov) * tanhf_(cl);
    Hleaf[(long)v * HP + t * 2 + e] = (f16_t)hl;   // pads (t>=75) exactly 0
    Cleaf[(long)v * HP + t * 2 + e] = (f16_t)cl;
  }
}

// Fused levels 17+16. A-operands live in registers (5 x f16x8 per lane);
// only B (U tile), the pass1->pass2 h handoff (A2), c handoff (C), and Wo
// are in LDS -> 32.9 KB -> 4 blocks/CU.
__global__ __launch_bounds__(256, 4) void fused17_kernel(
    const int* __restrict__ x_id, const f16_t* __restrict__ P,
    const f16_t* __restrict__ UreT, const f16_t* __restrict__ Hleaf,
    const f16_t* __restrict__ Cleaf, f16_t* __restrict__ Hout,
    f16_t* __restrict__ Cout, const float* __restrict__ W_out,
    const float* __restrict__ b_out, float* __restrict__ out) {
  __shared__ __align__(16) f16_t B_sh[128 * BST];
  __shared__ __align__(16) f16_t A2_sh[32 * AST];
  __shared__ f16_t C_sh[32 * CST];
  __shared__ __align__(16) f16_t Wo16[160 * 8];
  const int tid = threadIdx.x;
  const int wid = tid >> 6, lane = tid & 63, l15 = lane & 15, q = lane >> 4;
  const int p0 = blockIdx.x * 32;
  const int s1 = (1 << 17) - 1;
  const long childbase = (long)LEAF_S + 2 * p0;

  for (int idx = tid; idx < 1280; idx += 256) {
    int j = idx >> 3, m = idx & 7;
    Wo16[idx] = (j < 150 && m < 5) ? (f16_t)W_out[j * 5 + m] : (f16_t)0.0f;
  }

  // A registers: this lane's leaf row, its q-slice of all 160 k.
  const int row = 16 * wid + l15;
  const int xvrow = x_id[childbase + row];
  const f16_t* hrow = Hleaf + (long)xvrow * HP;
  f16x8 areg[5];
#pragma unroll
  for (int kx = 0; kx < 5; ++kx) areg[kx] = *(const f16x8*)&hrow[kx * 32 + q * 8];

  int xvp[2], xvl[2], xvr[2];
#pragma unroll
  for (int rr = 0; rr < 2; ++rr) {
    int pl = 8 * wid + 2 * q + rr;
    xvp[rr] = x_id[(long)s1 + p0 + pl];
    xvl[rr] = x_id[childbase + 2 * pl];
    xvr[rr] = x_id[childbase + 2 * pl + 1];
  }
  __syncthreads();   // Wo16 ready

  // leaf out-projection from registers
  {
    float o[5] = {0, 0, 0, 0, 0};
#pragma unroll
    for (int kx = 0; kx < 5; ++kx)
#pragma unroll
      for (int e = 0; e < 8; ++e) {
        int j = kx * 32 + q * 8 + e;
        float hv = (float)areg[kx][e];
        f16x8 w8 = *(const f16x8*)&Wo16[j * 8];
#pragma unroll
        for (int m = 0; m < 5; ++m) o[m] += hv * (float)w8[m];
      }
#pragma unroll
    for (int m = 0; m < 5; ++m) {
      float v = o[m];
      v += __shfl_xor(v, 16);
      v += __shfl_xor(v, 32);
      o[m] = v;
    }
    if (q == 0) {
      long base = (childbase + row) * 5;
#pragma unroll
      for (int m = 0; m < 5; ++m) out[base + m] = o[m] + b_out[m];
    }
  }

  // ---- pass 1: L17, 32 parents ----
  float oacc1[2][5] = {};
  for (int jt = 0; jt < 5; ++jt) {
    const int j0 = jt * 32;
    f32x4 acc[4][2];
#pragma unroll
    for (int g = 0; g < 4; ++g)
#pragma unroll
      for (int jh = 0; jh < 2; ++jh) acc[g][jh] = zero4();

    for (int kx = 0; kx < 5; ++kx) {
      stage_B(UreT, B_sh, tid, j0, kx * 32);
      __syncthreads();
#pragma unroll
      for (int g = 0; g < 4; ++g)
#pragma unroll
        for (int jh = 0; jh < 2; ++jh) {
          f16x8 bfr = read_B(B_sh, g * 32 + jh * 16 + l15, q);
          acc[g][jh] = __builtin_amdgcn_mfma_f32_16x16x32_f16(areg[kx], bfr, acc[g][jh], 0, 0, 0);
        }
      __syncthreads();
    }

#pragma unroll
    for (int rr = 0; rr < 2; ++rr) {
      const int r = rr * 2;
      const int pl = 8 * wid + 2 * q + rr;
      const f16_t* Prp = P + (long)xvp[rr] * NCOL;
      const f16_t* Crl = Cleaf + (long)xvl[rr] * HP;
      const f16_t* Crr = Cleaf + (long)xvr[rr] * HP;
#pragma unroll
      for (int jh = 0; jh < 2; ++jh) {
        const int j = j0 + jh * 16 + l15;
        f16x4 pp = *(const f16x4*)&Prp[j * 4];
        float ipre = (float)pp[0] + acc[0][jh][r] + acc[0][jh][r + 1];
        float opre = (float)pp[1] + acc[1][jh][r] + acc[1][jh][r + 1];
        float upre = (float)pp[2] + acc[2][jh][r] + acc[2][jh][r + 1];
        float pf   = (float)pp[3];
        float fl = sigf(pf + acc[3][jh][r]);
        float fr = sigf(pf + acc[3][jh][r + 1]);
        float cn = sigf(ipre) * tanhf_(upre) + fl * (float)Crl[j] + fr * (float)Crr[j];
        float hn = sigf(opre) * tanhf_(cn);
        A2_sh[pl * AST + j] = (f16_t)hn;
        C_sh[pl * CST + j] = (f16_t)cn;
        f16x8 w8 = *(const f16x8*)&Wo16[j * 8];
#pragma unroll
        for (int m = 0; m < 5; ++m) oacc1[rr][m] += hn * (float)w8[m];
      }
    }
  }
  __syncthreads();   // A2/C complete

  // L17 out-projection (producer-side, reduce over l15)
#pragma unroll
  for (int rr = 0; rr < 2; ++rr) {
    const int pl = 8 * wid + 2 * q + rr;
#pragma unroll
    for (int m = 0; m < 5; ++m) {
      float v = oacc1[rr][m];
      v += __shfl_xor(v, 1);
      v += __shfl_xor(v, 2);
      v += __shfl_xor(v, 4);
      v += __shfl_xor(v, 8);
      if (l15 == 0) out[((long)s1 + p0 + pl) * 5 + m] = v + b_out[m];
    }
  }

  // ---- pass 2: L16, 16 nodes (waves 0,1 compute; all stage B) ----
  const int s2 = (s1 - 1) >> 1;
  const int p02 = p0 >> 1;
  const bool act2 = (wid < 2);
  f16x8 a2reg[5];
  if (act2) {
#pragma unroll
    for (int kx = 0; kx < 5; ++kx)
      a2reg[kx] = *(const f16x8*)&A2_sh[(16 * wid + l15) * AST + kx * 32 + q * 8];
  }
  int xvp2[2];
#pragma unroll
  for (int rr = 0; rr < 2; ++rr) {
    int pl = 8 * wid + 2 * q + rr;
    xvp2[rr] = x_id[(long)s2 + p02 + (act2 ? pl : 0)];
  }

  float oacc2[2][5] = {};
  for (int jt = 0; jt < 5; ++jt) {
    const int j0 = jt * 32;
    f32x4 acc[4][2];
#pragma unroll
    for (int g = 0; g < 4; ++g)
#pragma unroll
      for (int jh = 0; jh < 2; ++jh) acc[g][jh] = zero4();

    for (int kx = 0; kx < 5; ++kx) {
      stage_B(UreT, B_sh, tid, j0, kx * 32);
      __syncthreads();
      if (act2) {
#pragma unroll
        for (int g = 0; g < 4; ++g)
#pragma unroll
          for (int jh = 0; jh < 2; ++jh) {
            f16x8 bfr = read_B(B_sh, g * 32 + jh * 16 + l15, q);
            acc[g][jh] = __builtin_amdgcn_mfma_f32_16x16x32_f16(a2reg[kx], bfr, acc[g][jh], 0, 0, 0);
          }
      }
      __syncthreads();
    }

    if (act2) {
#pragma unroll
      for (int rr = 0; rr < 2; ++rr) {
        const int r = rr * 2;
        const int lr0 = 16 * wid + q * 4 + r;   // 0..31
        const int pl = lr0 >> 1;                // 0..15
        const f16_t* Prp = P + (long)xvp2[rr] * NCOL;
#pragma unroll
        for (int jh = 0; jh < 2; ++jh) {
          const int j = j0 + jh * 16 + l15;
          f16x4 pp = *(const f16x4*)&Prp[j * 4];
          float ipre = (float)pp[0] + acc[0][jh][r] + acc[0][jh][r + 1];
          float opre = (float)pp[1] + acc[1][jh][r] + acc[1][jh][r + 1];
          float upre = (float)pp[2] + acc[2][jh][r] + acc[2][jh][r + 1];
          float pf   = (float)pp[3];
          float fl = sigf(pf + acc[3][jh][r]);
          float fr = sigf(pf + acc[3][jh][r + 1]);
          float cn = sigf(ipre) * tanhf_(upre) +
                     fl * (float)C_sh[lr0 * CST + j] + fr * (float)C_sh[(lr0 + 1) * CST + j];
          float hn = sigf(opre) * tanhf_(cn);
          Hout[(long)(p02 + pl) * HP + j] = (f16_t)hn;
          Cout[(long)(p02 + pl) * HP + j] = (f16_t)cn;
          f16x8 w8 = *(const f16x8*)&Wo16[j * 8];
#pragma unroll
          for (int m = 0; m < 5; ++m) oacc2[rr][m] += hn * (float)w8[m];
        }
      }
    }
  }

  if (act2) {
#pragma unroll
    for (int rr = 0; rr < 2; ++rr) {
      const int pl = 8 * wid + 2 * q + rr;
#pragma unroll
      for (int m = 0; m < 5; ++m) {
        float v = oacc2[rr][m];
        v += __shfl_xor(v, 1);
        v += __shfl_xor(v, 2);
        v += __shfl_xor(v, 4);
        v += __shfl_xor(v, 8);
        if (l15 == 0) out[((long)s2 + p02 + pl) * 5 + m] = v + b_out[m];
      }
    }
  }
}

// Single level, 32 parents/block, A in registers, producer projection.
__global__ __launch_bounds__(256, 4) void level_k(
    const int* __restrict__ x_id, const f16_t* __restrict__ P,
    const f16_t* __restrict__ UreT, const f16_t* __restrict__ Hc,
    const f16_t* __restrict__ Cc, f16_t* __restrict__ Hp,
    f16_t* __restrict__ Cp, const float* __restrict__ W_out,
    const float* __restrict__ b_out, float* __restrict__ out, int s, int M) {
  __shared__ __align__(16) f16_t B_sh[128 * BST];
  __shared__ __align__(16) f16_t Wo16[160 * 8];
  const int tid = threadIdx.x;
  const int wid = tid >> 6, lane = tid & 63, l15 = lane & 15, q = lane >> 4;
  const int p0 = blockIdx.x * 32;

  for (int idx = tid; idx < 1280; idx += 256) {
    int j = idx >> 3, m = idx & 7;
    Wo16[idx] = (j < 150 && m < 5) ? (f16_t)W_out[j * 5 + m] : (f16_t)0.0f;
  }

  const int row = 16 * wid + l15;
  const f16_t* hrow = Hc + (long)(2 * p0 + row) * HP;
  f16x8 areg[5];
#pragma unroll
  for (int kx = 0; kx < 5; ++kx) areg[kx] = *(const f16x8*)&hrow[kx * 32 + q * 8];

  int xvp[2];
#pragma unroll
  for (int rr = 0; rr < 2; ++rr) {
    int pl = 8 * wid + 2 * q + rr;
    xvp[rr] = x_id[(long)s + p0 + pl];
  }
  __syncthreads();   // Wo16 ready

  float oacc[2][5] = {};
  for (int jt = 0; jt < 5; ++jt) {
    const int j0 = jt * 32;
    f32x4 acc[4][2];
#pragma unroll
    for (int g = 0; g < 4; ++g)
#pragma unroll
      for (int jh = 0; jh < 2; ++jh) acc[g][jh] = zero4();

    for (int kx = 0; kx < 5; ++kx) {
      stage_B(UreT, B_sh, tid, j0, kx * 32);
      __syncthreads();
#pragma unroll
      for (int g = 0; g < 4; ++g)
#pragma unroll
        for (int jh = 0; jh < 2; ++jh) {
          f16x8 bfr = read_B(B_sh, g * 32 + jh * 16 + l15, q);
          acc[g][jh] = __builtin_amdgcn_mfma_f32_16x16x32_f16(areg[kx], bfr, acc[g][jh], 0, 0, 0);
        }
      __syncthreads();
    }

#pragma unroll
    for (int rr = 0; rr < 2; ++rr) {
      const int r = rr * 2;
      const int lr0 = 16 * wid + q * 4 + r;
      const int pl = lr0 >> 1;
      const f16_t* Prp = P + (long)xvp[rr] * NCOL;
#pragma unroll
      for (int jh = 0; jh < 2; ++jh) {
        const int j = j0 + jh * 16 + l15;
        f16x4 pp = *(const f16x4*)&Prp[j * 4];
        float ipre = (float)pp[0] + acc[0][jh][r] + acc[0][jh][r + 1];
        float opre = (float)pp[1] + acc[1][jh][r] + acc[1][jh][r + 1];
        float upre = (float)pp[2] + acc[2][jh][r] + acc[2][jh][r + 1];
        float pf   = (float)pp[3];
        float fl = sigf(pf + acc[3][jh][r]);
        float fr = sigf(pf + acc[3][jh][r + 1]);
        float clv = (float)Cc[(long)(2 * p0 + lr0) * HP + j];
        float crv = (float)Cc[(long)(2 * p0 + lr0 + 1) * HP + j];
        float cn = sigf(ipre) * tanhf_(upre) + fl * clv + fr * crv;
        float hn = sigf(opre) * tanhf_(cn);
        Hp[(long)(p0 + pl) * HP + j] = (f16_t)hn;
        Cp[(long)(p0 + pl) * HP + j] = (f16_t)cn;
        f16x8 w8 = *(const f16x8*)&Wo16[j * 8];
#pragma unroll
        for (int m = 0; m < 5; ++m) oacc[rr][m] += hn * (float)w8[m];
      }
    }
  }

#pragma unroll
  for (int rr = 0; rr < 2; ++rr) {
    const int pl = 8 * wid + 2 * q + rr;
#pragma unroll
    for (int m = 0; m < 5; ++m) {
      float v = oacc[rr][m];
      v += __shfl_xor(v, 1);
      v += __shfl_xor(v, 2);
      v += __shfl_xor(v, 4);
      v += __shfl_xor(v, 8);
      if (l15 == 0) out[((long)s + p0 + pl) * 5 + m] = v + b_out[m];
    }
  }
}

// Levels 5..0 in one block; each level projects itself (root at lvl 0).
__global__ __launch_bounds__(256, 4) void tail_kernel(
    const int* __restrict__ x_id, const f16_t* __restrict__ P,
    const f16_t* __restrict__ UreT, f16_t* __restrict__ HX, f16_t* __restrict__ HY,
    f16_t* __restrict__ CX, f16_t* __restrict__ CY, const float* __restrict__ W_out,
    const float* __restrict__ b_out, float* __restrict__ out) {
  __shared__ __align__(16) f16_t B_sh[128 * BST];
  __shared__ __align__(16) f16_t Wo16[160 * 8];
  const int tid = threadIdx.x;
  const int wid = tid >> 6, lane = tid & 63, l15 = lane & 15, q = lane >> 4;

  for (int idx = tid; idx < 1280; idx += 256) {
    int j = idx >> 3, m = idx & 7;
    Wo16[idx] = (j < 150 && m < 5) ? (f16_t)W_out[j * 5 + m] : (f16_t)0.0f;
  }

  for (int lvl = 5; lvl >= 0; --lvl) {
    const int s = (1 << lvl) - 1, M = 1 << lvl;
    const f16_t* hc = (lvl & 1) ? HX : HY;
    const f16_t* cc = (lvl & 1) ? CX : CY;
    f16_t* hp = (lvl & 1) ? HY : HX;
    f16_t* cp = (lvl & 1) ? CY : CX;
    int rowsValid = 2 * M;
    if (rowsValid > 64) rowsValid = 64;

    __threadfence();
    __syncthreads();   // prior level's global h/c visible; Wo16 ready; B_sh free

    const int row = 16 * wid + l15;
    f16x8 areg[5];
#pragma unroll
    for (int kx = 0; kx < 5; ++kx)
      areg[kx] = (row < rowsValid) ? *(const f16x8*)&hc[(long)row * HP + kx * 32 + q * 8]
                                   : zero8();

    int xvp[2]; bool valid[2];
#pragma unroll
    for (int rr = 0; rr < 2; ++rr) {
      int pl = 8 * wid + 2 * q + rr;
      valid[rr] = pl < M;
      xvp[rr] = x_id[(long)s + (valid[rr] ? pl : 0)];
    }

    float oacc[2][5] = {};
    for (int jt = 0; jt < 5; ++jt) {
      const int j0 = jt * 32;
      f32x4 acc[4][2];
#pragma unroll
      for (int g = 0; g < 4; ++g)
#pragma unroll
        for (int jh = 0; jh < 2; ++jh) acc[g][jh] = zero4();

      for (int kx = 0; kx < 5; ++kx) {
        stage_B(UreT, B_sh, tid, j0, kx * 32);
        __syncthreads();
#pragma unroll
        for (int g = 0; g < 4; ++g)
#pragma unroll
          for (int jh = 0; jh < 2; ++jh) {
            f16x8 bfr = read_B(B_sh, g * 32 + jh * 16 + l15, q);
            acc[g][jh] = __builtin_amdgcn_mfma_f32_16x16x32_f16(areg[kx], bfr, acc[g][jh], 0, 0, 0);
          }
        __syncthreads();
      }

#pragma unroll
      for (int rr = 0; rr < 2; ++rr) {
        const int r = rr * 2;
        const int lr0 = 16 * wid + q * 4 + r;
        const int pl = lr0 >> 1;
        const f16_t* Prp = P + (long)xvp[rr] * NCOL;
#pragma unroll
        for (int jh = 0; jh < 2; ++jh) {
          const int j = j0 + jh * 16 + l15;
          f16x4 pp = *(const f16x4*)&Prp[j * 4];
          float ipre = (float)pp[0] + acc[0][jh][r] + acc[0][jh][r + 1];
          float opre = (float)pp[1] + acc[1][jh][r] + acc[1][jh][r + 1];
          float upre = (float)pp[2] + acc[2][jh][r] + acc[2][jh][r + 1];
          float pf   = (float)pp[3];
          float fl = sigf(pf + acc[3][jh][r]);
          float fr = sigf(pf + acc[3][jh][r + 1]);
          float clv = valid[rr] ? (float)cc[(long)lr0 * HP + j] : 0.0f;
          float crv = valid[rr] ? (float)cc[(long)(lr0 + 1) * HP + j] : 0.0f;
          float cn = sigf(ipre) * tanhf_(upre) + fl * clv + fr * crv;
          float hn = sigf(opre) * tanhf_(cn);
          if (valid[rr]) {
            hp[(long)pl * HP + j] = (f16_t)hn;
            cp[(long)pl * HP + j] = (f16_t)cn;
          }
          f16x8 w8 = *(const f16x8*)&Wo16[j * 8];
#pragma unroll
          for (int m = 0; m < 5; ++m) oacc[rr][m] += hn * (float)w8[m];
        }
      }
    }

#pragma unroll
    for (int rr = 0; rr < 2; ++rr) {
      const int pl = 8 * wid + 2 * q + rr;
#pragma unroll
      for (int m = 0; m < 5; ++m) {
        float v = oacc[rr][m];
        v += __shfl_xor(v, 1);
        v += __shfl_xor(v, 2);
        v += __shfl_xor(v, 4);
        v += __shfl_xor(v, 8);
        if (l15 == 0 && valid[rr]) out[((long)s + pl) * 5 + m] = v + b_out[m];
      }
    }
  }
}

extern "C" void kernel_launch(void* const* d_in, const int* in_sizes, int n_in,
                              void* d_out, int out_size, void* d_ws, size_t ws_size,
                              hipStream_t stream) {
  const int* x_id   = (const int*)d_in[0];
  const float* emb  = (const float*)d_in[1];
  const float* W_iou = (const float*)d_in[2];
  const float* U_iou = (const float*)d_in[3];
  const float* b_iou = (const float*)d_in[4];
  const float* W_f   = (const float*)d_in[5];
  const float* U_f   = (const float*)d_in[6];
  const float* b_f   = (const float*)d_in[7];
  const float* W_out = (const float*)d_in[8];
  const float* b_out = (const float*)d_in[9];
  float* out = (float*)d_out;
  char* ws = (char*)d_ws;

  // workspace carve (bytes): total 180,503,040
  f16_t* WreT  = (f16_t*)(ws + 0);              // 409,600
  f16_t* UreT  = (f16_t*)(ws + 409600);         // 204,800
  float* bre   = (float*)(ws + 614400);         // 2,560
  f16_t* P     = (f16_t*)(ws + 616960);         // 64,000,000
  f16_t* Hleaf = (f16_t*)(ws + 64616960);       // 16,000,000
  f16_t* Cleaf = (f16_t*)(ws + 80616960);       // 16,000,000
  f16_t* HX    = (f16_t*)(ws + 96616960);       // 20,971,520 (65536 rows)
  f16_t* HY    = (f16_t*)(ws + 117588480);      // 20,971,520
  f16_t* CX    = (f16_t*)(ws + 138560000);      // 20,971,520
  f16_t* CY    = (f16_t*)(ws + 159531520);      // 20,971,520

  prep_params<<<1203, 256, 0, stream>>>(W_iou, U_iou, b_iou, W_f, U_f, b_f, WreT, UreT, bre);
  gemm_p<<<782, 256, 0, stream>>>(emb, WreT, bre, P);
  leafhc_kernel<<<15625, 256, 0, stream>>>(P, Hleaf, Cleaf);

  // levels 18(leaves)+17+16 -> HX/CX (L16 even -> X)
  fused17_kernel<<<4096, 256, 0, stream>>>(x_id, P, UreT, Hleaf, Cleaf, HX, CX,
                                           W_out, b_out, out);

  // levels 15..6: level L reads (L odd ? X : Y), writes (L even ? X : Y)
  for (int L = 15; L >= 6; --L) {
    int s = (1 << L) - 1, M = 1 << L;
    const f16_t* hc = (L & 1) ? HX : HY;
    const f16_t* cc = (L & 1) ? CX : CY;
    f16_t* hp = (L & 1) ? HY : HX;
    f16_t* cp = (L & 1) ? CY : CX;
    level_k<<<M / 32, 256, 0, stream>>>(x_id, P, UreT, hc, cc, hp, cp,
                                        W_out, b_out, out, s, M);
  }

  tail_kernel<<<1, 256, 0, stream>>>(x_id, P, UreT, HX, HY, CX, CY, W_out, b_out, out);

  (void)in_sizes; (void)n_in; (void)out_size; (void)ws_size;
}